// Round 2
// baseline (1636.764 us; speedup 1.0000x reference)
//
#include <hip/hip_runtime.h>
#include <hip/hip_bf16.h>
#include <stdint.h>

// B=8, N=2048, C=1024, H=16, D=64
using u16 = unsigned short;
typedef __attribute__((ext_vector_type(8))) short short8;       // bf16x8 MFMA frag
typedef __attribute__((ext_vector_type(8))) unsigned short ushort8;
typedef __attribute__((ext_vector_type(4))) unsigned short ushort4v;
typedef __attribute__((ext_vector_type(4))) float f32x4;

__device__ __forceinline__ float b2f(u16 b) {
  union { unsigned u; float f; } c; c.u = ((unsigned)b) << 16; return c.f;
}
__device__ __forceinline__ u16 f2b(float f) {   // RTNE fp32->bf16
  union { float f; unsigned u; } c; c.f = f;
  unsigned u = c.u;
  return (u16)((u + 0x7FFFu + ((u >> 16) & 1u)) >> 16);
}

// ---------------- fp32 -> bf16 convert (weights, context) ----------------
__global__ __launch_bounds__(256) void cvt_bf16_kernel(const float* __restrict__ in,
                                                       u16* __restrict__ out, long n) {
  long i = ((long)blockIdx.x * 256 + threadIdx.x) * 8;
  if (i >= n) return;
  float4 a = *(const float4*)(in + i);
  float4 b = *(const float4*)(in + i + 4);
  ushort8 o;
  o[0]=f2b(a.x); o[1]=f2b(a.y); o[2]=f2b(a.z); o[3]=f2b(a.w);
  o[4]=f2b(b.x); o[5]=f2b(b.y); o[6]=f2b(b.z); o[7]=f2b(b.w);
  *(ushort8*)(out + i) = o;
}

// ---------------- LayerNorm (fp32 in, bf16 out), one block per row of 1024 ----
__global__ __launch_bounds__(256) void ln_bf16_kernel(const float* __restrict__ x,
    const float* __restrict__ gamma, const float* __restrict__ beta,
    u16* __restrict__ out) {
  size_t row = blockIdx.x;
  int t = threadIdx.x;
  float4 v = ((const float4*)(x + row * 1024))[t];
  float s  = v.x + v.y + v.z + v.w;
  float s2 = v.x*v.x + v.y*v.y + v.z*v.z + v.w*v.w;
  #pragma unroll
  for (int o = 32; o; o >>= 1) { s += __shfl_xor(s, o); s2 += __shfl_xor(s2, o); }
  __shared__ float rs[4], rq[4];
  int w = t >> 6;
  if ((t & 63) == 0) { rs[w] = s; rq[w] = s2; }
  __syncthreads();
  s  = rs[0] + rs[1] + rs[2] + rs[3];
  s2 = rq[0] + rq[1] + rq[2] + rq[3];
  float mu  = s * (1.0f / 1024.0f);
  float var = fmaxf(s2 * (1.0f / 1024.0f) - mu * mu, 0.0f);
  float rr  = rsqrtf(var + 1e-5f);
  float4 g  = ((const float4*)gamma)[t];
  float4 bb = ((const float4*)beta)[t];
  ushort4v o;
  o[0] = f2b((v.x - mu) * rr * g.x + bb.x);
  o[1] = f2b((v.y - mu) * rr * g.y + bb.y);
  o[2] = f2b((v.z - mu) * rr * g.z + bb.z);
  o[3] = f2b((v.w - mu) * rr * g.w + bb.w);
  *(ushort4v*)(out + row * 1024 + t * 4) = o;
}

// ---------------- bf16 GEMM: C = scale*(A @ W^T) [+bias][relu][+res] -------
// A [M,K] row-major (lda), W [Nout,K] row-major (ldb). 128x128 tile, BK=64,
// 4 waves (2x2 of 64x64), mfma_f32_16x16x32_bf16, global_load_lds width=16.
#define BM 128
#define BN 128
#define BK 64

__device__ __forceinline__ void gload16(const void* g, void* l) {
  __builtin_amdgcn_global_load_lds(
      (const __attribute__((address_space(1))) void*)g,
      (__attribute__((address_space(3))) void*)l, 16, 0, 0);
}

template<int HAS_BIAS, int RELU, int HAS_RES, int OUT_BF16>
__global__ __launch_bounds__(256)
void gemm_bt(const u16* __restrict__ A, const u16* __restrict__ W,
             const float* __restrict__ bias, const float* __restrict__ res,
             void* __restrict__ Cv,
             int M, int Nn, int K, int lda, int ldb, int ldc,
             long long sAz, long long sWz, long long sCz, long long sRz,
             float scale)
{
  A += (size_t)blockIdx.z * sAz;
  W += (size_t)blockIdx.z * sWz;
  if (HAS_RES) res += (size_t)blockIdx.z * sRz;
  const size_t cz = (size_t)blockIdx.z * sCz;

  const int tid = threadIdx.x;
  const int i0 = blockIdx.y * BM;
  const int j0 = blockIdx.x * BN;
  __shared__ u16 sA[BM][BK];
  __shared__ u16 sB[BN][BK];
  const int lane = tid & 63;
  const int wv = tid >> 6, wr = wv >> 1, wc = wv & 1;
  const int r16 = lane & 15, kg = lane >> 4;        // kg in 0..3
  const int crow = tid >> 3;                        // staging row base 0..31
  const int ccol = (tid & 7) * 8;                   // staging col (bf16)

  f32x4 acc[4][4] = {};

  for (int k0 = 0; k0 < K; k0 += BK) {
    #pragma unroll
    for (int p = 0; p < 4; ++p) {
      int row = p * 32 + crow;
      gload16(A + (size_t)(i0 + row) * lda + k0 + ccol, &sA[row][ccol]);
    }
    #pragma unroll
    for (int p = 0; p < 4; ++p) {
      int row = p * 32 + crow;
      gload16(W + (size_t)(j0 + row) * ldb + k0 + ccol, &sB[row][ccol]);
    }
    __syncthreads();
    #pragma unroll
    for (int kk = 0; kk < 2; ++kk) {
      short8 a[4], b[4];
      #pragma unroll
      for (int i = 0; i < 4; ++i)
        a[i] = *(const short8*)&sA[wr * 64 + i * 16 + r16][kk * 32 + kg * 8];
      #pragma unroll
      for (int j = 0; j < 4; ++j)
        b[j] = *(const short8*)&sB[wc * 64 + j * 16 + r16][kk * 32 + kg * 8];
      #pragma unroll
      for (int i = 0; i < 4; ++i)
        #pragma unroll
        for (int j = 0; j < 4; ++j)
          acc[i][j] = __builtin_amdgcn_mfma_f32_16x16x32_bf16(a[i], b[j], acc[i][j], 0, 0, 0);
    }
    __syncthreads();
  }

  // epilogue: C/D frag mapping col=lane&15, row=(lane>>4)*4+reg (verified)
  #pragma unroll
  for (int j = 0; j < 4; ++j) {
    int col = j0 + wc * 64 + j * 16 + r16;
    float bj = HAS_BIAS ? bias[col] : 0.0f;
    #pragma unroll
    for (int i = 0; i < 4; ++i) {
      int row = i0 + wr * 64 + i * 16 + kg * 4;
      #pragma unroll
      for (int r = 0; r < 4; ++r) {
        float v = acc[i][j][r] * scale + bj;
        if (RELU) v = fmaxf(v, 0.0f);
        size_t idx = cz + (size_t)(row + r) * ldc + col;
        if (HAS_RES) v += res[(size_t)(row + r) * ldc + col];
        if (OUT_BF16) ((u16*)Cv)[idx] = f2b(v);
        else          ((float*)Cv)[idx] = v;
      }
    }
  }
}

// ---------------- self-attention over batch axis: [N,H] units of 8x8 --------
// qkv [16384, 3072] bf16 (rows = b*2048+n). sa [16384, 1024] bf16.
__global__ __launch_bounds__(256) void self_attn_kernel(const u16* __restrict__ qkv,
                                                        u16* __restrict__ sa) {
  int w = threadIdx.x >> 6, lane = threadIdx.x & 63;
  int unit = blockIdx.x * 4 + w;         // 0..32767
  int n = unit >> 4, h = unit & 15;
  __shared__ u16 sQ[4][8][64], sK[4][8][64], sV[4][8][64];
  __shared__ float sP[4][8][8];
  int li = lane >> 3, ld0 = (lane & 7) * 8;
  size_t base = ((size_t)li * 2048 + n) * 3072 + h * 64 + ld0;
  *(ushort8*)&sQ[w][li][ld0] = *(const ushort8*)(qkv + base);
  *(ushort8*)&sK[w][li][ld0] = *(const ushort8*)(qkv + base + 1024);
  *(ushort8*)&sV[w][li][ld0] = *(const ushort8*)(qkv + base + 2048);
  __syncthreads();
  // scores: lane = (i = li, j = sj)
  int sj = lane & 7;
  float s = 0.0f;
  #pragma unroll
  for (int c8 = 0; c8 < 8; ++c8) {
    ushort8 q8 = *(const ushort8*)&sQ[w][li][c8 * 8];
    ushort8 k8 = *(const ushort8*)&sK[w][sj][c8 * 8];
    #pragma unroll
    for (int q = 0; q < 8; ++q) s += b2f(q8[q]) * b2f(k8[q]);
  }
  s *= 0.125f;                            // D^-0.5, D=64
  float m = fmaxf(s, __shfl_xor(s, 1));
  m = fmaxf(m, __shfl_xor(m, 2));
  m = fmaxf(m, __shfl_xor(m, 4));
  float e = __expf(s - m);
  float sum = e;
  sum += __shfl_xor(sum, 1); sum += __shfl_xor(sum, 2); sum += __shfl_xor(sum, 4);
  sP[w][li][sj] = e / sum;
  __syncthreads();
  // out[i, d] = sum_j p[i][j] * v[j][d]; lane covers (i=li, d in [ld0,ld0+8))
  float o[8] = {0,0,0,0,0,0,0,0};
  #pragma unroll
  for (int j = 0; j < 8; ++j) {
    float pj = sP[w][li][j];
    ushort8 v8 = *(const ushort8*)&sV[w][j][ld0];
    #pragma unroll
    for (int dd = 0; dd < 8; ++dd) o[dd] += pj * b2f(v8[dd]);
  }
  ushort8 ov;
  #pragma unroll
  for (int dd = 0; dd < 8; ++dd) ov[dd] = f2b(o[dd]);
  *(ushort8*)(sa + ((size_t)li * 2048 + n) * 1024 + h * 64 + ld0) = ov;
}

// ---------------- row softmax: fp32 [16384, 2048] -> bf16 probs -------------
__global__ __launch_bounds__(256) void softmax_kernel(const float* __restrict__ s,
                                                      u16* __restrict__ p) {
  size_t row = blockIdx.x;
  const float4* sr = (const float4*)(s + row * 2048);
  int t = threadIdx.x;
  float4 a = sr[t * 2], b = sr[t * 2 + 1];
  float e[8] = {a.x, a.y, a.z, a.w, b.x, b.y, b.z, b.w};
  float mx = e[0];
  #pragma unroll
  for (int q = 1; q < 8; ++q) mx = fmaxf(mx, e[q]);
  #pragma unroll
  for (int o = 32; o; o >>= 1) mx = fmaxf(mx, __shfl_xor(mx, o));
  __shared__ float rm[4], rsum[4];
  int w = t >> 6;
  if ((t & 63) == 0) rm[w] = mx;
  __syncthreads();
  mx = fmaxf(fmaxf(rm[0], rm[1]), fmaxf(rm[2], rm[3]));
  float sum = 0.0f;
  #pragma unroll
  for (int q = 0; q < 8; ++q) { e[q] = __expf(e[q] - mx); sum += e[q]; }
  #pragma unroll
  for (int o = 32; o; o >>= 1) sum += __shfl_xor(sum, o);
  if ((t & 63) == 0) rsum[w] = sum;
  __syncthreads();
  sum = rsum[0] + rsum[1] + rsum[2] + rsum[3];
  float inv = 1.0f / sum;
  ushort8 o8;
  #pragma unroll
  for (int q = 0; q < 8; ++q) o8[q] = f2b(e[q] * inv);
  *(ushort8*)(p + row * 2048 + t * 8) = o8;
}

// ---------------- transpose v (cross-attn): vT[b][c][m] = kv[b*2048+m][1024+c]
__global__ __launch_bounds__(256) void transpose_v_kernel(const u16* __restrict__ kv,
                                                          u16* __restrict__ vT) {
  __shared__ u16 tile[64][72];           // +8 u16 pad (16B) keeps vec stores aligned
  int b = blockIdx.z;
  int m0 = blockIdx.x * 64, c0 = blockIdx.y * 64;
  int t = threadIdx.x;
  int r = t >> 2, cc = (t & 3) * 16;
  const u16* src = kv + ((size_t)b * 2048 + m0 + r) * 2048 + 1024 + c0 + cc;
  *(ushort8*)&tile[r][cc]     = *(const ushort8*)src;
  *(ushort8*)&tile[r][cc + 8] = *(const ushort8*)(src + 8);
  __syncthreads();
  int rc = t >> 2, mm0 = (t & 3) * 16;
  ushort8 o1, o2;
  #pragma unroll
  for (int q = 0; q < 8; ++q) { o1[q] = tile[mm0 + q][rc]; o2[q] = tile[mm0 + 8 + q][rc]; }
  u16* dst = vT + ((size_t)b * 1024 + c0 + rc) * 2048 + m0 + mm0;
  *(ushort8*)dst = o1;
  *(ushort8*)(dst + 8) = o2;
}

// ---------------------------------------------------------------------------
extern "C" void kernel_launch(void* const* d_in, const int* in_sizes, int n_in,
                              void* d_out, int out_size, void* d_ws, size_t ws_size,
                              hipStream_t stream) {
  const float* x     = (const float*)d_in[0];
  const float* ctx   = (const float*)d_in[1];
  const float* gamma = (const float*)d_in[2];
  const float* beta  = (const float*)d_in[3];
  const float* w_in  = (const float*)d_in[4];
  const float* b_in  = (const float*)d_in[5];
  const float* w_out = (const float*)d_in[6];
  const float* b_out = (const float*)d_in[7];
  const float* wq    = (const float*)d_in[8];
  const float* bq    = (const float*)d_in[9];
  const float* wkv   = (const float*)d_in[10];
  const float* bkv   = (const float*)d_in[11];
  const float* w1    = (const float*)d_in[12];
  const float* b1    = (const float*)d_in[13];
  const float* w2    = (const float*)d_in[14];
  const float* b2    = (const float*)d_in[15];
  float* xout = (float*)d_out;

  // -------- workspace layout (reuse regions by liveness; ~438 MB) ----------
  char* p = (char*)d_ws;
  auto take = [&](size_t bytes) { char* r = p; p += (bytes + 255) & ~(size_t)255; return r; };
  u16* wbi  = (u16*)take((size_t)3145728 * 2);   // w_in  bf16
  u16* wbo  = (u16*)take((size_t)1048576 * 2);   // w_out bf16
  u16* wbq  = (u16*)take((size_t)1048576 * 2);   // wq    bf16
  u16* wbkv = (u16*)take((size_t)4194304 * 2);   // wkv   bf16
  u16* wb1  = (u16*)take((size_t)4194304 * 2);   // w1    bf16
  u16* wb2  = (u16*)take((size_t)4194304 * 2);   // w2    bf16
  u16* xnb  = (u16*)take((size_t)16777216 * 2);  // LN output (reused 3x)
  u16* sab  = (u16*)take((size_t)16777216 * 2);  // sa -> q -> vT
  float* x1 = (float*)take((size_t)16777216 * 4);// x after self-attn
  u16* kvb  = (u16*)take((size_t)33554432 * 2);  // kv projection
  u16* ctxb = (u16*)take((size_t)33554432 * 2);  // ctx bf16 -> probs
  char* big = take((size_t)134217728);           // qkv -> scores(f32) -> h1
  u16*   qkvb    = (u16*)big;
  float* scoresf = (float*)big;
  u16*   h1b     = (u16*)big;
  u16*   probs   = ctxb;
  u16*   qb      = sab;
  u16*   vTb     = sab;

  dim3 blk(256);
  auto cvt = [&](const float* in, u16* out, long n) {
    cvt_bf16_kernel<<<dim3((unsigned)(n / 2048)), blk, 0, stream>>>(in, out, n);
  };
  cvt(w_in,  wbi,  3145728);
  cvt(w_out, wbo,  1048576);
  cvt(wq,    wbq,  1048576);
  cvt(wkv,   wbkv, 4194304);
  cvt(w1,    wb1,  4194304);
  cvt(w2,    wb2,  4194304);
  cvt(ctx,   ctxb, 33554432);

  // ---- self-attention block ----
  ln_bf16_kernel<<<dim3(16384), blk, 0, stream>>>(x, gamma, beta, xnb);
  gemm_bt<1,0,0,1><<<dim3(24, 128, 1), blk, 0, stream>>>(xnb, wbi, b_in, nullptr, qkvb,
      16384, 3072, 1024, 1024, 1024, 3072, 0, 0, 0, 0, 1.0f);
  self_attn_kernel<<<dim3(8192), blk, 0, stream>>>(qkvb, sab);
  gemm_bt<1,0,1,0><<<dim3(8, 128, 1), blk, 0, stream>>>(sab, wbo, b_out, x, x1,
      16384, 1024, 1024, 1024, 1024, 1024, 0, 0, 0, 0, 1.0f);

  // ---- cross-attention block ----
  ln_bf16_kernel<<<dim3(16384), blk, 0, stream>>>(x1, gamma, beta, xnb);
  gemm_bt<1,0,0,1><<<dim3(8, 128, 1), blk, 0, stream>>>(xnb, wbq, bq, nullptr, qb,
      16384, 1024, 1024, 1024, 1024, 1024, 0, 0, 0, 0, 1.0f);
  gemm_bt<1,0,0,1><<<dim3(16, 128, 1), blk, 0, stream>>>(ctxb, wbkv, bkv, nullptr, kvb,
      16384, 2048, 2048, 2048, 2048, 2048, 0, 0, 0, 0, 1.0f);
  // scores[b] = q_b @ k_b^T * 0.125 (head-summed quirk: full-C dot)
  gemm_bt<0,0,0,0><<<dim3(16, 16, 8), blk, 0, stream>>>(qb, kvb, nullptr, nullptr, scoresf,
      2048, 2048, 1024, 1024, 2048, 2048,
      2048LL * 1024, 2048LL * 2048, 2048LL * 2048, 0, 0.125f);
  softmax_kernel<<<dim3(16384), blk, 0, stream>>>(scoresf, probs);
  transpose_v_kernel<<<dim3(32, 16, 8), blk, 0, stream>>>(kvb, vTb);
  // out[b] = probs_b @ v_b (+ residual x1) -> d_out (fp32)
  gemm_bt<0,0,1,0><<<dim3(8, 16, 8), blk, 0, stream>>>(probs, vTb, nullptr, x1, xout,
      2048, 1024, 2048, 2048, 2048, 1024,
      2048LL * 2048, 1024LL * 2048, 2048LL * 1024, 2048LL * 1024, 1.0f);

  // ---- FFN block ----
  ln_bf16_kernel<<<dim3(16384), blk, 0, stream>>>(xout, gamma, beta, xnb);
  gemm_bt<1,1,0,1><<<dim3(32, 128, 1), blk, 0, stream>>>(xnb, wb1, b1, nullptr, h1b,
      16384, 4096, 1024, 1024, 1024, 4096, 0, 0, 0, 0, 1.0f);
  gemm_bt<1,0,1,0><<<dim3(8, 128, 1), blk, 0, stream>>>(h1b, wb2, b2, xout, xout,
      16384, 1024, 4096, 4096, 4096, 1024, 0, 0, 0, 0, 1.0f);
}

// Round 7
// 1629.855 us; speedup vs baseline: 1.0042x; 1.0042x over previous
//
#include <hip/hip_runtime.h>
#include <hip/hip_bf16.h>
#include <stdint.h>

// B=8, N=2048, C=1024, H=16, D=64
using u16 = unsigned short;
typedef __attribute__((ext_vector_type(8))) short short8;       // bf16x8 MFMA frag
typedef __attribute__((ext_vector_type(8))) unsigned short ushort8;
typedef __attribute__((ext_vector_type(4))) unsigned short ushort4v;
typedef __attribute__((ext_vector_type(4))) float f32x4;

__device__ __forceinline__ float b2f(u16 b) {
  union { unsigned u; float f; } c; c.u = ((unsigned)b) << 16; return c.f;
}
__device__ __forceinline__ u16 f2b(float f) {   // RTNE fp32->bf16
  union { float f; unsigned u; } c; c.f = f;
  unsigned u = c.u;
  return (u16)((u + 0x7FFFu + ((u >> 16) & 1u)) >> 16);
}

// ---------------- fp32 -> bf16 convert (weights, context) ----------------
__global__ __launch_bounds__(256) void cvt_bf16_kernel(const float* __restrict__ in,
                                                       u16* __restrict__ out, long n) {
  long i = ((long)blockIdx.x * 256 + threadIdx.x) * 8;
  if (i >= n) return;
  float4 a = *(const float4*)(in + i);
  float4 b = *(const float4*)(in + i + 4);
  ushort8 o;
  o[0]=f2b(a.x); o[1]=f2b(a.y); o[2]=f2b(a.z); o[3]=f2b(a.w);
  o[4]=f2b(b.x); o[5]=f2b(b.y); o[6]=f2b(b.z); o[7]=f2b(b.w);
  *(ushort8*)(out + i) = o;
}

// ---------------- LayerNorm (fp32 in, bf16 out), one block per row of 1024 ----
__global__ __launch_bounds__(256) void ln_bf16_kernel(const float* __restrict__ x,
    const float* __restrict__ gamma, const float* __restrict__ beta,
    u16* __restrict__ out) {
  size_t row = blockIdx.x;
  int t = threadIdx.x;
  float4 v = ((const float4*)(x + row * 1024))[t];
  float s  = v.x + v.y + v.z + v.w;
  float s2 = v.x*v.x + v.y*v.y + v.z*v.z + v.w*v.w;
  #pragma unroll
  for (int o = 32; o; o >>= 1) { s += __shfl_xor(s, o); s2 += __shfl_xor(s2, o); }
  __shared__ float rs[4], rq[4];
  int w = t >> 6;
  if ((t & 63) == 0) { rs[w] = s; rq[w] = s2; }
  __syncthreads();
  s  = rs[0] + rs[1] + rs[2] + rs[3];
  s2 = rq[0] + rq[1] + rq[2] + rq[3];
  float mu  = s * (1.0f / 1024.0f);
  float var = fmaxf(s2 * (1.0f / 1024.0f) - mu * mu, 0.0f);
  float rr  = rsqrtf(var + 1e-5f);
  float4 g  = ((const float4*)gamma)[t];
  float4 bb = ((const float4*)beta)[t];
  ushort4v o;
  o[0] = f2b((v.x - mu) * rr * g.x + bb.x);
  o[1] = f2b((v.y - mu) * rr * g.y + bb.y);
  o[2] = f2b((v.z - mu) * rr * g.z + bb.z);
  o[3] = f2b((v.w - mu) * rr * g.w + bb.w);
  *(ushort4v*)(out + row * 1024 + t * 4) = o;
}

// ---------------- bf16 GEMM: C = scale*(A @ W^T) [+bias][relu][+res] -------
// A [M,K] row-major (lda), W [Nout,K] row-major (ldb). 128x128 tile, BK=64,
// 4 waves (2x2 of 64x64), mfma_f32_16x16x32_bf16, global_load_lds width=16.
// T1: XCD-chunked bijective blockIdx swizzle. T3-min: double-buffered LDS,
// stage(t+1) issued before compute(t), single barrier per K-step.
#define BM 128
#define BN 128
#define BK 64

__device__ __forceinline__ void gload16(const void* g, void* l) {
  __builtin_amdgcn_global_load_lds(
      (const __attribute__((address_space(1))) void*)g,
      (__attribute__((address_space(3))) void*)l, 16, 0, 0);
}

template<int HAS_BIAS, int RELU, int HAS_RES, int OUT_BF16>
__global__ __launch_bounds__(256)
void gemm_bt(const u16* __restrict__ A, const u16* __restrict__ W,
             const float* __restrict__ bias, const float* __restrict__ res,
             void* __restrict__ Cv,
             int M, int Nn, int K, int lda, int ldb, int ldc,
             long long sAz, long long sWz, long long sCz, long long sRz,
             float scale)
{
  A += (size_t)blockIdx.z * sAz;
  W += (size_t)blockIdx.z * sWz;
  if (HAS_RES) res += (size_t)blockIdx.z * sRz;
  const size_t cz = (size_t)blockIdx.z * sCz;

  // ---- T1: bijective XCD-chunked swizzle of (x,y) within this z-slice ----
  const int gx = gridDim.x;
  const int nwg = gx * gridDim.y;
  const int orig = blockIdx.y * gx + blockIdx.x;
  const int q = nwg >> 3, r = nwg & 7;
  const int xcd = orig & 7;
  const int cbase = (xcd < r) ? xcd * (q + 1) : r * (q + 1) + (xcd - r) * q;
  const int logical = cbase + (orig >> 3);
  const int i0 = (logical / gx) * BM;
  const int j0 = (logical % gx) * BN;

  const int tid = threadIdx.x;
  __shared__ u16 sA[2][BM][BK];
  __shared__ u16 sB[2][BN][BK];
  const int lane = tid & 63;
  const int wv = tid >> 6, wr = wv >> 1, wc = wv & 1;
  const int r16 = lane & 15, kg = lane >> 4;        // kg in 0..3
  const int crow = tid >> 3;                        // staging row base 0..31
  const int ccol = (tid & 7) * 8;                   // staging col (bf16)

  f32x4 acc[4][4] = {};

  auto stage = [&](int c, int k0) {
    #pragma unroll
    for (int p = 0; p < 4; ++p) {
      int row = p * 32 + crow;
      gload16(A + (size_t)(i0 + row) * lda + k0 + ccol, &sA[c][row][ccol]);
    }
    #pragma unroll
    for (int p = 0; p < 4; ++p) {
      int row = p * 32 + crow;
      gload16(W + (size_t)(j0 + row) * ldb + k0 + ccol, &sB[c][row][ccol]);
    }
  };

  stage(0, 0);
  __syncthreads();                 // vmcnt(0) drained by compiler before barrier
  int c = 0;
  for (int k0 = 0; k0 < K; k0 += BK) {
    if (k0 + BK < K) stage(c ^ 1, k0 + BK);   // issue next-tile loads first
    #pragma unroll
    for (int kk = 0; kk < 2; ++kk) {
      short8 a[4], b[4];
      #pragma unroll
      for (int i = 0; i < 4; ++i)
        a[i] = *(const short8*)&sA[c][wr * 64 + i * 16 + r16][kk * 32 + kg * 8];
      #pragma unroll
      for (int j = 0; j < 4; ++j)
        b[j] = *(const short8*)&sB[c][wc * 64 + j * 16 + r16][kk * 32 + kg * 8];
      #pragma unroll
      for (int i = 0; i < 4; ++i)
        #pragma unroll
        for (int j = 0; j < 4; ++j)
          acc[i][j] = __builtin_amdgcn_mfma_f32_16x16x32_bf16(a[i], b[j], acc[i][j], 0, 0, 0);
    }
    __syncthreads();               // drains vm (stage landed) + all reads of buf c
    c ^= 1;
  }

  // epilogue: C/D frag mapping col=lane&15, row=(lane>>4)*4+reg (verified)
  #pragma unroll
  for (int j = 0; j < 4; ++j) {
    int col = j0 + wc * 64 + j * 16 + r16;
    float bj = HAS_BIAS ? bias[col] : 0.0f;
    #pragma unroll
    for (int i = 0; i < 4; ++i) {
      int row = i0 + wr * 64 + i * 16 + kg * 4;
      #pragma unroll
      for (int r2 = 0; r2 < 4; ++r2) {
        float v = acc[i][j][r2] * scale + bj;
        if (RELU) v = fmaxf(v, 0.0f);
        size_t idx = cz + (size_t)(row + r2) * ldc + col;
        if (HAS_RES) v += res[(size_t)(row + r2) * ldc + col];
        if (OUT_BF16) ((u16*)Cv)[idx] = f2b(v);
        else          ((float*)Cv)[idx] = v;
      }
    }
  }
}

// ---------------- self-attention over batch axis: [N,H] units of 8x8 --------
// qkv [16384, 3072] bf16 (rows = b*2048+n). sa [16384, 1024] bf16.
__global__ __launch_bounds__(256) void self_attn_kernel(const u16* __restrict__ qkv,
                                                        u16* __restrict__ sa) {
  int w = threadIdx.x >> 6, lane = threadIdx.x & 63;
  int unit = blockIdx.x * 4 + w;         // 0..32767
  int n = unit >> 4, h = unit & 15;
  __shared__ u16 sQ[4][8][64], sK[4][8][64], sV[4][8][64];
  __shared__ float sP[4][8][8];
  int li = lane >> 3, ld0 = (lane & 7) * 8;
  size_t base = ((size_t)li * 2048 + n) * 3072 + h * 64 + ld0;
  *(ushort8*)&sQ[w][li][ld0] = *(const ushort8*)(qkv + base);
  *(ushort8*)&sK[w][li][ld0] = *(const ushort8*)(qkv + base + 1024);
  *(ushort8*)&sV[w][li][ld0] = *(const ushort8*)(qkv + base + 2048);
  __syncthreads();
  // scores: lane = (i = li, j = sj)
  int sj = lane & 7;
  float s = 0.0f;
  #pragma unroll
  for (int c8 = 0; c8 < 8; ++c8) {
    ushort8 q8 = *(const ushort8*)&sQ[w][li][c8 * 8];
    ushort8 k8 = *(const ushort8*)&sK[w][sj][c8 * 8];
    #pragma unroll
    for (int q = 0; q < 8; ++q) s += b2f(q8[q]) * b2f(k8[q]);
  }
  s *= 0.125f;                            // D^-0.5, D=64
  float m = fmaxf(s, __shfl_xor(s, 1));
  m = fmaxf(m, __shfl_xor(m, 2));
  m = fmaxf(m, __shfl_xor(m, 4));
  float e = __expf(s - m);
  float sum = e;
  sum += __shfl_xor(sum, 1); sum += __shfl_xor(sum, 2); sum += __shfl_xor(sum, 4);
  sP[w][li][sj] = e / sum;
  __syncthreads();
  // out[i, d] = sum_j p[i][j] * v[j][d]; lane covers (i=li, d in [ld0,ld0+8))
  float o[8] = {0,0,0,0,0,0,0,0};
  #pragma unroll
  for (int j = 0; j < 8; ++j) {
    float pj = sP[w][li][j];
    ushort8 v8 = *(const ushort8*)&sV[w][j][ld0];
    #pragma unroll
    for (int dd = 0; dd < 8; ++dd) o[dd] += pj * b2f(v8[dd]);
  }
  ushort8 ov;
  #pragma unroll
  for (int dd = 0; dd < 8; ++dd) ov[dd] = f2b(o[dd]);
  *(ushort8*)(sa + ((size_t)li * 2048 + n) * 1024 + h * 64 + ld0) = ov;
}

// ---------------- row softmax: fp32 [16384, 2048] -> bf16 probs -------------
__global__ __launch_bounds__(256) void softmax_kernel(const float* __restrict__ s,
                                                      u16* __restrict__ p) {
  size_t row = blockIdx.x;
  const float4* sr = (const float4*)(s + row * 2048);
  int t = threadIdx.x;
  float4 a = sr[t * 2], b = sr[t * 2 + 1];
  float e[8] = {a.x, a.y, a.z, a.w, b.x, b.y, b.z, b.w};
  float mx = e[0];
  #pragma unroll
  for (int q = 1; q < 8; ++q) mx = fmaxf(mx, e[q]);
  #pragma unroll
  for (int o = 32; o; o >>= 1) mx = fmaxf(mx, __shfl_xor(mx, o));
  __shared__ float rm[4], rsum[4];
  int w = t >> 6;
  if ((t & 63) == 0) rm[w] = mx;
  __syncthreads();
  mx = fmaxf(fmaxf(rm[0], rm[1]), fmaxf(rm[2], rm[3]));
  float sum = 0.0f;
  #pragma unroll
  for (int q = 0; q < 8; ++q) { e[q] = __expf(e[q] - mx); sum += e[q]; }
  #pragma unroll
  for (int o = 32; o; o >>= 1) sum += __shfl_xor(sum, o);
  if ((t & 63) == 0) rsum[w] = sum;
  __syncthreads();
  sum = rsum[0] + rsum[1] + rsum[2] + rsum[3];
  float inv = 1.0f / sum;
  ushort8 o8;
  #pragma unroll
  for (int q = 0; q < 8; ++q) o8[q] = f2b(e[q] * inv);
  *(ushort8*)(p + row * 2048 + t * 8) = o8;
}

// ---------------- transpose v (cross-attn): vT[b][c][m] = kv[b*2048+m][1024+c]
__global__ __launch_bounds__(256) void transpose_v_kernel(const u16* __restrict__ kv,
                                                          u16* __restrict__ vT) {
  __shared__ u16 tile[64][72];           // +8 u16 pad (16B) keeps vec stores aligned
  int b = blockIdx.z;
  int m0 = blockIdx.x * 64, c0 = blockIdx.y * 64;
  int t = threadIdx.x;
  int r = t >> 2, cc = (t & 3) * 16;
  const u16* src = kv + ((size_t)b * 2048 + m0 + r) * 2048 + 1024 + c0 + cc;
  *(ushort8*)&tile[r][cc]     = *(const ushort8*)src;
  *(ushort8*)&tile[r][cc + 8] = *(const ushort8*)(src + 8);
  __syncthreads();
  int rc = t >> 2, mm0 = (t & 3) * 16;
  ushort8 o1, o2;
  #pragma unroll
  for (int q = 0; q < 8; ++q) { o1[q] = tile[mm0 + q][rc]; o2[q] = tile[mm0 + 8 + q][rc]; }
  u16* dst = vT + ((size_t)b * 1024 + c0 + rc) * 2048 + m0 + mm0;
  *(ushort8*)dst = o1;
  *(ushort8*)(dst + 8) = o2;
}

// ---------------------------------------------------------------------------
extern "C" void kernel_launch(void* const* d_in, const int* in_sizes, int n_in,
                              void* d_out, int out_size, void* d_ws, size_t ws_size,
                              hipStream_t stream) {
  const float* x     = (const float*)d_in[0];
  const float* ctx   = (const float*)d_in[1];
  const float* gamma = (const float*)d_in[2];
  const float* beta  = (const float*)d_in[3];
  const float* w_in  = (const float*)d_in[4];
  const float* b_in  = (const float*)d_in[5];
  const float* w_out = (const float*)d_in[6];
  const float* b_out = (const float*)d_in[7];
  const float* wq    = (const float*)d_in[8];
  const float* bq    = (const float*)d_in[9];
  const float* wkv   = (const float*)d_in[10];
  const float* bkv   = (const float*)d_in[11];
  const float* w1    = (const float*)d_in[12];
  const float* b1    = (const float*)d_in[13];
  const float* w2    = (const float*)d_in[14];
  const float* b2    = (const float*)d_in[15];
  float* xout = (float*)d_out;

  // -------- workspace layout (reuse regions by liveness; ~438 MB) ----------
  char* p = (char*)d_ws;
  auto take = [&](size_t bytes) { char* r = p; p += (bytes + 255) & ~(size_t)255; return r; };
  u16* wbi  = (u16*)take((size_t)3145728 * 2);   // w_in  bf16
  u16* wbo  = (u16*)take((size_t)1048576 * 2);   // w_out bf16
  u16* wbq  = (u16*)take((size_t)1048576 * 2);   // wq    bf16
  u16* wbkv = (u16*)take((size_t)4194304 * 2);   // wkv   bf16
  u16* wb1  = (u16*)take((size_t)4194304 * 2);   // w1    bf16
  u16* wb2  = (u16*)take((size_t)4194304 * 2);   // w2    bf16
  u16* xnb  = (u16*)take((size_t)16777216 * 2);  // LN output (reused 3x)
  u16* sab  = (u16*)take((size_t)16777216 * 2);  // sa -> q -> vT
  float* x1 = (float*)take((size_t)16777216 * 4);// x after self-attn
  u16* kvb  = (u16*)take((size_t)33554432 * 2);  // kv projection
  u16* ctxb = (u16*)take((size_t)33554432 * 2);  // ctx bf16 -> probs
  char* big = take((size_t)134217728);           // qkv -> scores(f32) -> h1
  u16*   qkvb    = (u16*)big;
  float* scoresf = (float*)big;
  u16*   h1b     = (u16*)big;
  u16*   probs   = ctxb;
  u16*   qb      = sab;
  u16*   vTb     = sab;

  dim3 blk(256);
  auto cvt = [&](const float* in, u16* out, long n) {
    cvt_bf16_kernel<<<dim3((unsigned)(n / 2048)), blk, 0, stream>>>(in, out, n);
  };
  cvt(w_in,  wbi,  3145728);
  cvt(w_out, wbo,  1048576);
  cvt(wq,    wbq,  1048576);
  cvt(wkv,   wbkv, 4194304);
  cvt(w1,    wb1,  4194304);
  cvt(w2,    wb2,  4194304);
  cvt(ctx,   ctxb, 33554432);

  // ---- self-attention block ----
  ln_bf16_kernel<<<dim3(16384), blk, 0, stream>>>(x, gamma, beta, xnb);
  gemm_bt<1,0,0,1><<<dim3(24, 128, 1), blk, 0, stream>>>(xnb, wbi, b_in, nullptr, qkvb,
      16384, 3072, 1024, 1024, 1024, 3072, 0, 0, 0, 0, 1.0f);
  self_attn_kernel<<<dim3(8192), blk, 0, stream>>>(qkvb, sab);
  gemm_bt<1,0,1,0><<<dim3(8, 128, 1), blk, 0, stream>>>(sab, wbo, b_out, x, x1,
      16384, 1024, 1024, 1024, 1024, 1024, 0, 0, 0, 0, 1.0f);

  // ---- cross-attention block ----
  ln_bf16_kernel<<<dim3(16384), blk, 0, stream>>>(x1, gamma, beta, xnb);
  gemm_bt<1,0,0,1><<<dim3(8, 128, 1), blk, 0, stream>>>(xnb, wbq, bq, nullptr, qb,
      16384, 1024, 1024, 1024, 1024, 1024, 0, 0, 0, 0, 1.0f);
  gemm_bt<1,0,0,1><<<dim3(16, 128, 1), blk, 0, stream>>>(ctxb, wbkv, bkv, nullptr, kvb,
      16384, 2048, 2048, 2048, 2048, 2048, 0, 0, 0, 0, 1.0f);
  // scores[b] = q_b @ k_b^T * 0.125 (head-summed quirk: full-C dot)
  gemm_bt<0,0,0,0><<<dim3(16, 16, 8), blk, 0, stream>>>(qb, kvb, nullptr, nullptr, scoresf,
      2048, 2048, 1024, 1024, 2048, 2048,
      2048LL * 1024, 2048LL * 2048, 2048LL * 2048, 0, 0.125f);
  softmax_kernel<<<dim3(16384), blk, 0, stream>>>(scoresf, probs);
  transpose_v_kernel<<<dim3(32, 16, 8), blk, 0, stream>>>(kvb, vTb);
  // out[b] = probs_b @ v_b (+ residual x1) -> d_out (fp32)
  gemm_bt<0,0,1,0><<<dim3(8, 16, 8), blk, 0, stream>>>(probs, vTb, nullptr, x1, xout,
      2048, 1024, 2048, 2048, 2048, 1024,
      2048LL * 2048, 1024LL * 2048, 2048LL * 1024, 2048LL * 1024, 1.0f);

  // ---- FFN block ----
  ln_bf16_kernel<<<dim3(16384), blk, 0, stream>>>(xout, gamma, beta, xnb);
  gemm_bt<1,1,0,1><<<dim3(32, 128, 1), blk, 0, stream>>>(xnb, wb1, b1, nullptr, h1b,
      16384, 4096, 1024, 1024, 1024, 4096, 0, 0, 0, 0, 1.0f);
  gemm_bt<1,0,1,0><<<dim3(8, 128, 1), blk, 0, stream>>>(h1b, wb2, b2, xout, xout,
      16384, 1024, 4096, 4096, 4096, 1024, 0, 0, 0, 0, 1.0f);
}

// Round 9
// 1435.830 us; speedup vs baseline: 1.1399x; 1.1351x over previous
//
#include <hip/hip_runtime.h>
#include <hip/hip_bf16.h>
#include <stdint.h>

// B=8, N=2048, C=1024, H=16, D=64
using u16 = unsigned short;
typedef __attribute__((ext_vector_type(8))) short short8;       // bf16x8 MFMA frag
typedef __attribute__((ext_vector_type(8))) unsigned short ushort8;
typedef __attribute__((ext_vector_type(4))) unsigned short ushort4v;
typedef __attribute__((ext_vector_type(4))) float f32x4;

__device__ __forceinline__ float b2f(u16 b) {
  union { unsigned u; float f; } c; c.u = ((unsigned)b) << 16; return c.f;
}
__device__ __forceinline__ u16 f2b(float f) {   // RTNE fp32->bf16
  union { float f; unsigned u; } c; c.f = f;
  unsigned u = c.u;
  return (u16)((u + 0x7FFFu + ((u >> 16) & 1u)) >> 16);
}

// ---------------- fp32 -> bf16 convert (weights, context) ----------------
__global__ __launch_bounds__(256) void cvt_bf16_kernel(const float* __restrict__ in,
                                                       u16* __restrict__ out, long n) {
  long i = ((long)blockIdx.x * 256 + threadIdx.x) * 8;
  if (i >= n) return;
  float4 a = *(const float4*)(in + i);
  float4 b = *(const float4*)(in + i + 4);
  ushort8 o;
  o[0]=f2b(a.x); o[1]=f2b(a.y); o[2]=f2b(a.z); o[3]=f2b(a.w);
  o[4]=f2b(b.x); o[5]=f2b(b.y); o[6]=f2b(b.z); o[7]=f2b(b.w);
  *(ushort8*)(out + i) = o;
}

// ---------------- LayerNorm (fp32 in, bf16 out), one block per row of 1024 ----
__global__ __launch_bounds__(256) void ln_bf16_kernel(const float* __restrict__ x,
    const float* __restrict__ gamma, const float* __restrict__ beta,
    u16* __restrict__ out) {
  size_t row = blockIdx.x;
  int t = threadIdx.x;
  float4 v = ((const float4*)(x + row * 1024))[t];
  float s  = v.x + v.y + v.z + v.w;
  float s2 = v.x*v.x + v.y*v.y + v.z*v.z + v.w*v.w;
  #pragma unroll
  for (int o = 32; o; o >>= 1) { s += __shfl_xor(s, o); s2 += __shfl_xor(s2, o); }
  __shared__ float rs[4], rq[4];
  int w = t >> 6;
  if ((t & 63) == 0) { rs[w] = s; rq[w] = s2; }
  __syncthreads();
  s  = rs[0] + rs[1] + rs[2] + rs[3];
  s2 = rq[0] + rq[1] + rq[2] + rq[3];
  float mu  = s * (1.0f / 1024.0f);
  float var = fmaxf(s2 * (1.0f / 1024.0f) - mu * mu, 0.0f);
  float rr  = rsqrtf(var + 1e-5f);
  float4 g  = ((const float4*)gamma)[t];
  float4 bb = ((const float4*)beta)[t];
  ushort4v o;
  o[0] = f2b((v.x - mu) * rr * g.x + bb.x);
  o[1] = f2b((v.y - mu) * rr * g.y + bb.y);
  o[2] = f2b((v.z - mu) * rr * g.z + bb.z);
  o[3] = f2b((v.w - mu) * rr * g.w + bb.w);
  *(ushort4v*)(out + row * 1024 + t * 4) = o;
}

// ---------------- bf16 GEMM: C = scale*(A @ W^T) [+bias][relu][+res] -------
// A [M,K] row-major (lda), W [Nout,K] row-major (ldb). 128x128 tile, BK=64,
// 4 waves (2x2 of 64x64), mfma_f32_16x16x32_bf16, global_load_lds width=16.
// T1: XCD-chunked bijective blockIdx swizzle. T3-min: double-buffered LDS,
// stage(t+1) issued before compute(t), single barrier per K-step.
// T2 (rule #21 pairing): LDS dest stays LINEAR (gload_lds needs base+lane*16);
// the 16B-chunk index within each 128B row is XOR-swizzled on the GLOBAL
// source and identically on the ds_read side: chunk_phys = chunk ^ (row&7).
// Breaks the stride-128B 16-way bank conflict (5.03e7 extra cyc/dispatch, r7).
#define BM 128
#define BN 128
#define BK 64

__device__ __forceinline__ void gload16(const void* g, void* l) {
  __builtin_amdgcn_global_load_lds(
      (const __attribute__((address_space(1))) void*)g,
      (__attribute__((address_space(3))) void*)l, 16, 0, 0);
}

template<int HAS_BIAS, int RELU, int HAS_RES, int OUT_BF16>
__global__ __launch_bounds__(256)
void gemm_bt(const u16* __restrict__ A, const u16* __restrict__ W,
             const float* __restrict__ bias, const float* __restrict__ res,
             void* __restrict__ Cv,
             int M, int Nn, int K, int lda, int ldb, int ldc,
             long long sAz, long long sWz, long long sCz, long long sRz,
             float scale)
{
  A += (size_t)blockIdx.z * sAz;
  W += (size_t)blockIdx.z * sWz;
  if (HAS_RES) res += (size_t)blockIdx.z * sRz;
  const size_t cz = (size_t)blockIdx.z * sCz;

  // ---- T1: bijective XCD-chunked swizzle of (x,y) within this z-slice ----
  const int gx = gridDim.x;
  const int nwg = gx * gridDim.y;
  const int orig = blockIdx.y * gx + blockIdx.x;
  const int q = nwg >> 3, r = nwg & 7;
  const int xcd = orig & 7;
  const int cbase = (xcd < r) ? xcd * (q + 1) : r * (q + 1) + (xcd - r) * q;
  const int logical = cbase + (orig >> 3);
  const int i0 = (logical / gx) * BM;
  const int j0 = (logical % gx) * BN;

  const int tid = threadIdx.x;
  __shared__ u16 sA[2][BM][BK];
  __shared__ u16 sB[2][BN][BK];
  const int lane = tid & 63;
  const int wv = tid >> 6, wr = wv >> 1, wc = wv & 1;
  const int r16 = lane & 15, kg = lane >> 4;        // kg in 0..3
  const int crow = tid >> 3;                        // staging row base 0..31
  const int ccol = (tid & 7) * 8;                   // LDS dest col (LINEAR, bf16)
  // T2 source swizzle: this lane fetches the 16B chunk that belongs at its
  // linear LDS slot under chunk_phys = chunk_log ^ (row&7). row&7 == crow&7.
  const int scol = ((tid & 7) ^ (crow & 7)) * 8;    // global col (bf16)

  f32x4 acc[4][4] = {};

  auto stage = [&](int c, int k0) {
    #pragma unroll
    for (int p = 0; p < 4; ++p) {
      int row = p * 32 + crow;
      gload16(A + (size_t)(i0 + row) * lda + k0 + scol, &sA[c][row][ccol]);
    }
    #pragma unroll
    for (int p = 0; p < 4; ++p) {
      int row = p * 32 + crow;
      gload16(W + (size_t)(j0 + row) * ldb + k0 + scol, &sB[c][row][ccol]);
    }
  };

  stage(0, 0);
  __syncthreads();                 // vmcnt(0) drained by compiler before barrier
  int c = 0;
  for (int k0 = 0; k0 < K; k0 += BK) {
    if (k0 + BK < K) stage(c ^ 1, k0 + BK);   // issue next-tile loads first
    #pragma unroll
    for (int kk = 0; kk < 2; ++kk) {
      short8 a[4], b[4];
      #pragma unroll
      for (int i = 0; i < 4; ++i)
        a[i] = *(const short8*)&sA[c][wr * 64 + i * 16 + r16]
                                  [(((kk << 2) | kg) ^ (r16 & 7)) * 8];
      #pragma unroll
      for (int j = 0; j < 4; ++j)
        b[j] = *(const short8*)&sB[c][wc * 64 + j * 16 + r16]
                                  [(((kk << 2) | kg) ^ (r16 & 7)) * 8];
      #pragma unroll
      for (int i = 0; i < 4; ++i)
        #pragma unroll
        for (int j = 0; j < 4; ++j)
          acc[i][j] = __builtin_amdgcn_mfma_f32_16x16x32_bf16(a[i], b[j], acc[i][j], 0, 0, 0);
    }
    __syncthreads();               // drains vm (stage landed) + all reads of buf c
    c ^= 1;
  }

  // epilogue: C/D frag mapping col=lane&15, row=(lane>>4)*4+reg (verified)
  #pragma unroll
  for (int j = 0; j < 4; ++j) {
    int col = j0 + wc * 64 + j * 16 + r16;
    float bj = HAS_BIAS ? bias[col] : 0.0f;
    #pragma unroll
    for (int i = 0; i < 4; ++i) {
      int row = i0 + wr * 64 + i * 16 + kg * 4;
      #pragma unroll
      for (int r2 = 0; r2 < 4; ++r2) {
        float v = acc[i][j][r2] * scale + bj;
        if (RELU) v = fmaxf(v, 0.0f);
        size_t idx = cz + (size_t)(row + r2) * ldc + col;
        if (HAS_RES) v += res[(size_t)(row + r2) * ldc + col];
        if (OUT_BF16) ((u16*)Cv)[idx] = f2b(v);
        else          ((float*)Cv)[idx] = v;
      }
    }
  }
}

// ---------------- self-attention over batch axis: [N,H] units of 8x8 --------
// qkv [16384, 3072] bf16 (rows = b*2048+n). sa [16384, 1024] bf16.
__global__ __launch_bounds__(256) void self_attn_kernel(const u16* __restrict__ qkv,
                                                        u16* __restrict__ sa) {
  int w = threadIdx.x >> 6, lane = threadIdx.x & 63;
  int unit = blockIdx.x * 4 + w;         // 0..32767
  int n = unit >> 4, h = unit & 15;
  __shared__ u16 sQ[4][8][64], sK[4][8][64], sV[4][8][64];
  __shared__ float sP[4][8][8];
  int li = lane >> 3, ld0 = (lane & 7) * 8;
  size_t base = ((size_t)li * 2048 + n) * 3072 + h * 64 + ld0;
  *(ushort8*)&sQ[w][li][ld0] = *(const ushort8*)(qkv + base);
  *(ushort8*)&sK[w][li][ld0] = *(const ushort8*)(qkv + base + 1024);
  *(ushort8*)&sV[w][li][ld0] = *(const ushort8*)(qkv + base + 2048);
  __syncthreads();
  // scores: lane = (i = li, j = sj)
  int sj = lane & 7;
  float s = 0.0f;
  #pragma unroll
  for (int c8 = 0; c8 < 8; ++c8) {
    ushort8 q8 = *(const ushort8*)&sQ[w][li][c8 * 8];
    ushort8 k8 = *(const ushort8*)&sK[w][sj][c8 * 8];
    #pragma unroll
    for (int q = 0; q < 8; ++q) s += b2f(q8[q]) * b2f(k8[q]);
  }
  s *= 0.125f;                            // D^-0.5, D=64
  float m = fmaxf(s, __shfl_xor(s, 1));
  m = fmaxf(m, __shfl_xor(m, 2));
  m = fmaxf(m, __shfl_xor(m, 4));
  float e = __expf(s - m);
  float sum = e;
  sum += __shfl_xor(sum, 1); sum += __shfl_xor(sum, 2); sum += __shfl_xor(sum, 4);
  sP[w][li][sj] = e / sum;
  __syncthreads();
  // out[i, d] = sum_j p[i][j] * v[j][d]; lane covers (i=li, d in [ld0,ld0+8))
  float o[8] = {0,0,0,0,0,0,0,0};
  #pragma unroll
  for (int j = 0; j < 8; ++j) {
    float pj = sP[w][li][j];
    ushort8 v8 = *(const ushort8*)&sV[w][j][ld0];
    #pragma unroll
    for (int dd = 0; dd < 8; ++dd) o[dd] += pj * b2f(v8[dd]);
  }
  ushort8 ov;
  #pragma unroll
  for (int dd = 0; dd < 8; ++dd) ov[dd] = f2b(o[dd]);
  *(ushort8*)(sa + ((size_t)li * 2048 + n) * 1024 + h * 64 + ld0) = ov;
}

// ---------------- row softmax: fp32 [16384, 2048] -> bf16 probs -------------
__global__ __launch_bounds__(256) void softmax_kernel(const float* __restrict__ s,
                                                      u16* __restrict__ p) {
  size_t row = blockIdx.x;
  const float4* sr = (const float4*)(s + row * 2048);
  int t = threadIdx.x;
  float4 a = sr[t * 2], b = sr[t * 2 + 1];
  float e[8] = {a.x, a.y, a.z, a.w, b.x, b.y, b.z, b.w};
  float mx = e[0];
  #pragma unroll
  for (int q = 1; q < 8; ++q) mx = fmaxf(mx, e[q]);
  #pragma unroll
  for (int o = 32; o; o >>= 1) mx = fmaxf(mx, __shfl_xor(mx, o));
  __shared__ float rm[4], rsum[4];
  int w = t >> 6;
  if ((t & 63) == 0) rm[w] = mx;
  __syncthreads();
  mx = fmaxf(fmaxf(rm[0], rm[1]), fmaxf(rm[2], rm[3]));
  float sum = 0.0f;
  #pragma unroll
  for (int q = 0; q < 8; ++q) { e[q] = __expf(e[q] - mx); sum += e[q]; }
  #pragma unroll
  for (int o = 32; o; o >>= 1) sum += __shfl_xor(sum, o);
  if ((t & 63) == 0) rsum[w] = sum;
  __syncthreads();
  sum = rsum[0] + rsum[1] + rsum[2] + rsum[3];
  float inv = 1.0f / sum;
  ushort8 o8;
  #pragma unroll
  for (int q = 0; q < 8; ++q) o8[q] = f2b(e[q] * inv);
  *(ushort8*)(p + row * 2048 + t * 8) = o8;
}

// ---------------- transpose v (cross-attn): vT[b][c][m] = kv[b*2048+m][1024+c]
__global__ __launch_bounds__(256) void transpose_v_kernel(const u16* __restrict__ kv,
                                                          u16* __restrict__ vT) {
  __shared__ u16 tile[64][72];           // +8 u16 pad (16B) keeps vec stores aligned
  int b = blockIdx.z;
  int m0 = blockIdx.x * 64, c0 = blockIdx.y * 64;
  int t = threadIdx.x;
  int r = t >> 2, cc = (t & 3) * 16;
  const u16* src = kv + ((size_t)b * 2048 + m0 + r) * 2048 + 1024 + c0 + cc;
  *(ushort8*)&tile[r][cc]     = *(const ushort8*)src;
  *(ushort8*)&tile[r][cc + 8] = *(const ushort8*)(src + 8);
  __syncthreads();
  int rc = t >> 2, mm0 = (t & 3) * 16;
  ushort8 o1, o2;
  #pragma unroll
  for (int q = 0; q < 8; ++q) { o1[q] = tile[mm0 + q][rc]; o2[q] = tile[mm0 + 8 + q][rc]; }
  u16* dst = vT + ((size_t)b * 1024 + c0 + rc) * 2048 + m0 + mm0;
  *(ushort8*)dst = o1;
  *(ushort8*)(dst + 8) = o2;
}

// ---------------------------------------------------------------------------
extern "C" void kernel_launch(void* const* d_in, const int* in_sizes, int n_in,
                              void* d_out, int out_size, void* d_ws, size_t ws_size,
                              hipStream_t stream) {
  const float* x     = (const float*)d_in[0];
  const float* ctx   = (const float*)d_in[1];
  const float* gamma = (const float*)d_in[2];
  const float* beta  = (const float*)d_in[3];
  const float* w_in  = (const float*)d_in[4];
  const float* b_in  = (const float*)d_in[5];
  const float* w_out = (const float*)d_in[6];
  const float* b_out = (const float*)d_in[7];
  const float* wq    = (const float*)d_in[8];
  const float* bq    = (const float*)d_in[9];
  const float* wkv   = (const float*)d_in[10];
  const float* bkv   = (const float*)d_in[11];
  const float* w1    = (const float*)d_in[12];
  const float* b1    = (const float*)d_in[13];
  const float* w2    = (const float*)d_in[14];
  const float* b2    = (const float*)d_in[15];
  float* xout = (float*)d_out;

  // -------- workspace layout (reuse regions by liveness; ~438 MB) ----------
  char* p = (char*)d_ws;
  auto take = [&](size_t bytes) { char* r = p; p += (bytes + 255) & ~(size_t)255; return r; };
  u16* wbi  = (u16*)take((size_t)3145728 * 2);   // w_in  bf16
  u16* wbo  = (u16*)take((size_t)1048576 * 2);   // w_out bf16
  u16* wbq  = (u16*)take((size_t)1048576 * 2);   // wq    bf16
  u16* wbkv = (u16*)take((size_t)4194304 * 2);   // wkv   bf16
  u16* wb1  = (u16*)take((size_t)4194304 * 2);   // w1    bf16
  u16* wb2  = (u16*)take((size_t)4194304 * 2);   // w2    bf16
  u16* xnb  = (u16*)take((size_t)16777216 * 2);  // LN output (reused 3x)
  u16* sab  = (u16*)take((size_t)16777216 * 2);  // sa -> q -> vT
  float* x1 = (float*)take((size_t)16777216 * 4);// x after self-attn
  u16* kvb  = (u16*)take((size_t)33554432 * 2);  // kv projection
  u16* ctxb = (u16*)take((size_t)33554432 * 2);  // ctx bf16 -> probs
  char* big = take((size_t)134217728);           // qkv -> scores(f32) -> h1
  u16*   qkvb    = (u16*)big;
  float* scoresf = (float*)big;
  u16*   h1b     = (u16*)big;
  u16*   probs   = ctxb;
  u16*   qb      = sab;
  u16*   vTb     = sab;

  dim3 blk(256);
  auto cvt = [&](const float* in, u16* out, long n) {
    cvt_bf16_kernel<<<dim3((unsigned)(n / 2048)), blk, 0, stream>>>(in, out, n);
  };
  cvt(w_in,  wbi,  3145728);
  cvt(w_out, wbo,  1048576);
  cvt(wq,    wbq,  1048576);
  cvt(wkv,   wbkv, 4194304);
  cvt(w1,    wb1,  4194304);
  cvt(w2,    wb2,  4194304);
  cvt(ctx,   ctxb, 33554432);

  // ---- self-attention block ----
  ln_bf16_kernel<<<dim3(16384), blk, 0, stream>>>(x, gamma, beta, xnb);
  gemm_bt<1,0,0,1><<<dim3(24, 128, 1), blk, 0, stream>>>(xnb, wbi, b_in, nullptr, qkvb,
      16384, 3072, 1024, 1024, 1024, 3072, 0, 0, 0, 0, 1.0f);
  self_attn_kernel<<<dim3(8192), blk, 0, stream>>>(qkvb, sab);
  gemm_bt<1,0,1,0><<<dim3(8, 128, 1), blk, 0, stream>>>(sab, wbo, b_out, x, x1,
      16384, 1024, 1024, 1024, 1024, 1024, 0, 0, 0, 0, 1.0f);

  // ---- cross-attention block ----
  ln_bf16_kernel<<<dim3(16384), blk, 0, stream>>>(x1, gamma, beta, xnb);
  gemm_bt<1,0,0,1><<<dim3(8, 128, 1), blk, 0, stream>>>(xnb, wbq, bq, nullptr, qb,
      16384, 1024, 1024, 1024, 1024, 1024, 0, 0, 0, 0, 1.0f);
  gemm_bt<1,0,0,1><<<dim3(16, 128, 1), blk, 0, stream>>>(ctxb, wbkv, bkv, nullptr, kvb,
      16384, 2048, 2048, 2048, 2048, 2048, 0, 0, 0, 0, 1.0f);
  // scores[b] = q_b @ k_b^T * 0.125 (head-summed quirk: full-C dot)
  gemm_bt<0,0,0,0><<<dim3(16, 16, 8), blk, 0, stream>>>(qb, kvb, nullptr, nullptr, scoresf,
      2048, 2048, 1024, 1024, 2048, 2048,
      2048LL * 1024, 2048LL * 2048, 2048LL * 2048, 0, 0.125f);
  softmax_kernel<<<dim3(16384), blk, 0, stream>>>(scoresf, probs);
  transpose_v_kernel<<<dim3(32, 16, 8), blk, 0, stream>>>(kvb, vTb);
  // out[b] = probs_b @ v_b (+ residual x1) -> d_out (fp32)
  gemm_bt<0,0,1,0><<<dim3(8, 16, 8), blk, 0, stream>>>(probs, vTb, nullptr, x1, xout,
      2048, 1024, 2048, 2048, 2048, 1024,
      2048LL * 2048, 1024LL * 2048, 2048LL * 1024, 2048LL * 1024, 1.0f);

  // ---- FFN block ----
  ln_bf16_kernel<<<dim3(16384), blk, 0, stream>>>(xout, gamma, beta, xnb);
  gemm_bt<1,1,0,1><<<dim3(32, 128, 1), blk, 0, stream>>>(xnb, wb1, b1, nullptr, h1b,
      16384, 4096, 1024, 1024, 1024, 4096, 0, 0, 0, 0, 1.0f);
  gemm_bt<1,0,1,0><<<dim3(8, 128, 1), blk, 0, stream>>>(h1b, wb2, b2, xout, xout,
      16384, 1024, 4096, 4096, 4096, 1024, 0, 0, 0, 0, 1.0f);
}